// Round 1
// baseline (2462.966 us; speedup 1.0000x reference)
//
#include <hip/hip_runtime.h>
#include <hip/hip_bf16.h>
#include <float.h>
#include <math.h>

// Problem constants
#define NL    32
#define BEAM  8
#define KV2   2
#define HEADS 8
#define SEQ   1024
#define HDIM  64
#define VOCAB 50257
#define HIST  128
#define TOPK  8

// slab = per-(l,b) contiguous block: KV2*HEADS*SEQ*HDIM = 1,048,576 floats
// = 262,144 float4 (2^18)
static constexpr long long KV_FLOATS = (long long)NL * BEAM * KV2 * HEADS * SEQ * HDIM; // 2^28

// ws layout (4-byte slots):
//   float [0,64)        : per-block running max m       (block = row*8+part)
//   float [64,128)      : per-block running sum s (rel. to m)
//   float [128,640)     : per-block top8 values   [block][8]
//   int   [640,1152)    : per-block top8 vocab idx [block][8]
//   int   [1152,1160)   : beam_index[8]
#define WS_M    0
#define WS_S    64
#define WS_TV   128
#define WS_TI   640
#define WS_BIDX 1152

// ---------------------------------------------------------------------------
// Kernel 1: per (row, vocab-chunk) partial LSE + top-8.
// grid = 64 blocks (row = bid>>3, part = bid&7), 256 threads.
// ---------------------------------------------------------------------------
__global__ void topk_partial(const float* __restrict__ logits,
                             float* __restrict__ wsf, int* __restrict__ wsi)
{
    const int row  = blockIdx.x >> 3;
    const int part = blockIdx.x & 7;
    const int CHUNK = 6283;                       // ceil(50257/8)
    const int begin = part * CHUNK;
    const int end   = min(begin + CHUNK, VOCAB);  // last chunk = 6276
    const float* lg = logits + row * VOCAB;
    const int t = threadIdx.x;

    float m = -FLT_MAX, s = 0.f;
    float tv[TOPK]; int ti[TOPK];
#pragma unroll
    for (int k = 0; k < TOPK; ++k) { tv[k] = -FLT_MAX; ti[k] = 0x7fffffff; }

    for (int v = begin + t; v < end; v += 256) {
        float x = lg[v];
        // online logsumexp
        if (x > m) { s = s * expf(m - x) + 1.f; m = x; }
        else       { s += expf(x - m); }
        // sorted-descending top-8 insert; tie -> lower index wins
        if (x > tv[TOPK-1] || (x == tv[TOPK-1] && v < ti[TOPK-1])) {
            int k = TOPK - 1;
            while (k > 0 && (x > tv[k-1] || (x == tv[k-1] && v < ti[k-1]))) {
                tv[k] = tv[k-1]; ti[k] = ti[k-1]; --k;
            }
            tv[k] = x; ti[k] = v;
        }
    }

    __shared__ float sm[256], ss[256];
    __shared__ float sv[256][TOPK];
    __shared__ int   si[256][TOPK];
    sm[t] = m; ss[t] = s;
#pragma unroll
    for (int k = 0; k < TOPK; ++k) { sv[t][k] = tv[k]; si[t][k] = ti[k]; }
    __syncthreads();

    for (int off = 128; off > 0; off >>= 1) {
        if (t < off) {
            // combine (m,s)
            float m1 = sm[t], s1 = ss[t];
            float m2 = sm[t + off], s2 = ss[t + off];
            float M = fmaxf(m1, m2);
            sm[t] = M;
            ss[t] = s1 * expf(m1 - M) + s2 * expf(m2 - M);
            // merge two sorted-desc top8 lists
            float av[TOPK], bv[TOPK], ov[TOPK];
            int   ai[TOPK], bi[TOPK], oi[TOPK];
#pragma unroll
            for (int k = 0; k < TOPK; ++k) {
                av[k] = sv[t][k];       ai[k] = si[t][k];
                bv[k] = sv[t+off][k];   bi[k] = si[t+off][k];
            }
            int ia = 0, ib = 0;
#pragma unroll
            for (int k = 0; k < TOPK; ++k) {
                bool takeA = (av[ia] > bv[ib]) ||
                             (av[ia] == bv[ib] && ai[ia] < bi[ib]);
                if (takeA) { ov[k] = av[ia]; oi[k] = ai[ia]; ++ia; }
                else       { ov[k] = bv[ib]; oi[k] = bi[ib]; ++ib; }
            }
#pragma unroll
            for (int k = 0; k < TOPK; ++k) { sv[t][k] = ov[k]; si[t][k] = oi[k]; }
        }
        __syncthreads();
    }

    if (t == 0) {
        wsf[WS_M + blockIdx.x] = sm[0];
        wsf[WS_S + blockIdx.x] = ss[0];
#pragma unroll
        for (int k = 0; k < TOPK; ++k) {
            wsf[WS_TV + blockIdx.x * TOPK + k] = sv[0][k];
            wsi[WS_TI + blockIdx.x * TOPK + k] = si[0][k];
        }
    }
}

// ---------------------------------------------------------------------------
// Kernel 2: merge partials, global beam top-8, write small outputs.
// 1 block, 256 threads (thread 0 does the tiny serial selection).
// ---------------------------------------------------------------------------
__global__ void finalize(const float* __restrict__ prev,
                         const int* __restrict__ save_id,
                         float* __restrict__ out,
                         float* __restrict__ wsf, int* __restrict__ wsi)
{
    __shared__ int   s_beam[BEAM];
    __shared__ int   s_tbi[BEAM];
    __shared__ float s_prob[BEAM];

    if (threadIdx.x == 0) {
        float cv[64]; int ci[64];   // candidates [row*8 + rank]
        for (int r = 0; r < BEAM; ++r) {
            // combine LSE over 8 parts
            float M = -FLT_MAX;
            for (int p = 0; p < 8; ++p) M = fmaxf(M, wsf[WS_M + r*8 + p]);
            float S = 0.f;
            for (int p = 0; p < 8; ++p)
                S += wsf[WS_S + r*8 + p] * expf(wsf[WS_M + r*8 + p] - M);
            float lse = M + logf(S);
            // gather 64 partial candidates, select row top-8
            float pv[64]; int pi[64];
            for (int p = 0; p < 8; ++p)
                for (int k = 0; k < TOPK; ++k) {
                    pv[p*8 + k] = wsf[WS_TV + (r*8 + p) * TOPK + k];
                    pi[p*8 + k] = wsi[WS_TI + (r*8 + p) * TOPK + k];
                }
            for (int k = 0; k < TOPK; ++k) {
                int best = -1;
                for (int j = 0; j < 64; ++j) {
                    if (pi[j] < 0) continue;
                    if (best < 0 || pv[j] > pv[best] ||
                        (pv[j] == pv[best] && pi[j] < pi[best])) best = j;
                }
                cv[r*8 + k] = pv[best] - lse + prev[r];
                ci[r*8 + k] = pi[best];
                pi[best] = -1;
            }
        }
        // stage 2: top-8 of 64 by (value desc, flat index asc)
        bool used[64];
        for (int j = 0; j < 64; ++j) used[j] = false;
        for (int k = 0; k < TOPK; ++k) {
            int best = -1;
            for (int j = 0; j < 64; ++j) {
                if (used[j]) continue;
                if (best < 0 || cv[j] > cv[best]) best = j; // asc scan + strict > == lower-idx tiebreak
            }
            used[best] = true;
            s_beam[k] = best >> 3;
            s_tbi[k]  = ci[best];
            s_prob[k] = cv[best];
            wsi[WS_BIDX + k] = best >> 3;
        }
    }
    __syncthreads();

    // small outputs (all stored as fp32 values in the flat out buffer)
    float* out_save = out + KV_FLOATS;              // 8*129
    float* out_prob = out_save + BEAM * (HIST + 1); // 8
    float* out_tbi  = out_prob + BEAM;              // 8
    float* out_mli  = out_tbi + BEAM;               // 1
    for (int i = threadIdx.x; i < BEAM * (HIST + 1); i += blockDim.x) {
        int b = i / (HIST + 1), j = i - b * (HIST + 1);
        out_save[i] = (j < HIST) ? (float)save_id[s_beam[b] * HIST + j]
                                 : (float)s_tbi[b];
    }
    if (threadIdx.x < BEAM) {
        out_prob[threadIdx.x] = s_prob[threadIdx.x];
        out_tbi[threadIdx.x]  = (float)s_tbi[threadIdx.x];
    }
    if (threadIdx.x == 0) out_mli[0] = (float)s_tbi[0];
}

// ---------------------------------------------------------------------------
// Kernel 3: kv gather — 1 GiB copy. Each block copies 1024 consecutive float4
// (16 KiB) of the output; a block never straddles a (l,b) slab boundary.
// ---------------------------------------------------------------------------
__global__ void kv_gather(const float* __restrict__ kv,
                          float* __restrict__ out,
                          const int* __restrict__ beam_idx)
{
    const long long base = (long long)blockIdx.x * 1024; // float4 index
    const int slab = (int)(base >> 18);                  // / 262144
    const int l = slab >> 3, b = slab & 7;
    const int sb = beam_idx[b];
    const long long srcSlab = ((long long)(l * 8 + sb)) << 18;

    const float4* s4 = (const float4*)kv + srcSlab + (base & 0x3FFFFLL);
    float4*       d4 = (float4*)out + base;
#pragma unroll
    for (int k = 0; k < 4; ++k) {
        int o = k * 256 + threadIdx.x;
        d4[o] = s4[o];
    }
}

extern "C" void kernel_launch(void* const* d_in, const int* in_sizes, int n_in,
                              void* d_out, int out_size, void* d_ws, size_t ws_size,
                              hipStream_t stream)
{
    const float* kv      = (const float*)d_in[0];
    const float* logits  = (const float*)d_in[1];
    const int*   save_id = (const int*)d_in[2];
    const float* prev    = (const float*)d_in[3];
    float* out = (float*)d_out;
    float* wsf = (float*)d_ws;
    int*   wsi = (int*)d_ws;

    topk_partial<<<64, 256, 0, stream>>>(logits, wsf, wsi);
    finalize<<<1, 256, 0, stream>>>(prev, save_id, out, wsf, wsi);
    // 2^26 float4 / 1024 per block = 65536 blocks
    kv_gather<<<65536, 256, 0, stream>>>(kv, out, wsi + WS_BIDX);
}